// Round 1
// 450.232 us; speedup vs baseline: 1.0630x; 1.0630x over previous
//
#include <hip/hip_runtime.h>
#include <hip/hip_bf16.h>

// ---------------------------------------------------------------------------
// FieldPredictionNetwork. R10: attack the latency-bound pointwise/GEMV family
// (pw_lin 72.5us @ VALUBusy 32%, HBM 4.4%). Three fixes, all fp32-exact:
//  1. pw_lin: unroll-by-4 inner loops (broadcast ds_read_b128 of the tile),
//     Q staged TRANSPOSED in LDS via global_load_lds DMA (conflict-free
//     per-lane b64 reads), l1W row via rolling 1-ahead register prefetch,
//     y->z in-place in ONE 16KB tile (wave-private rows => no extra barrier).
//     LDS 48KB -> 3 blocks/CU. 1 barrier instead of 3.
//  2. dft64_rows: unroll-by-4 (b128 broadcast reads), 1024 blocks x 32 rows.
//  3. final_out: unroll-by-2 (b128 broadcast reads), rolling Wout prefetch,
//     1024 blocks x 32 rows.
// fft_stage1/2 (spill-sensitive) untouched this round.
// ---------------------------------------------------------------------------

#define PI2F 6.28318530717958647692f

typedef __attribute__((ext_vector_type(8))) short short8;
typedef __attribute__((ext_vector_type(4))) float f32x4;

__device__ __forceinline__ unsigned short f2bf(float f) {
  unsigned int u = __float_as_uint(f);
  u += 0x7fff + ((u >> 16) & 1);          // RN-even
  return (unsigned short)(u >> 16);
}
__device__ __forceinline__ unsigned int pack_bf16x2(float a, float b) {
  return (unsigned int)f2bf(a) | ((unsigned int)f2bf(b) << 16);
}

// async 16B global->LDS DMA; lds dest must be wave-uniform (HW adds lane*16)
__device__ __forceinline__ void gl2lds16(const void* gptr, const void* lptr) {
  __builtin_amdgcn_global_load_lds(
      (const __attribute__((address_space(1))) unsigned int*)(unsigned long long)gptr,
      (__attribute__((address_space(3))) unsigned int*)(unsigned int)(unsigned long long)lptr,
      16, 0, 0);
}

// ---------------------------------------------------------------------------
// f32 -> bf16 pack (4 elems/thread)
// ---------------------------------------------------------------------------
__global__ __launch_bounds__(256) void f32_to_bf16_k(
    const float* __restrict__ src, unsigned short* __restrict__ dst, int n4)
{
  int i = blockIdx.x * 256 + threadIdx.x;
  if (i < n4) {
    float4 v = ((const float4*)src)[i];
    uint2 p;
    p.x = pack_bf16x2(v.x, v.y);
    p.y = pack_bf16x2(v.z, v.w);
    ((uint2*)dst)[i] = p;
  }
}

// ---------------------------------------------------------------------------
// GEMM: C = relu(A @ Bw^T + bias). A [M,K] bf16, Bw [N,K] bf16, bias f32.
// OUT = ushort (bf16) or float. BK=64, 4 waves, async LDS staging + swizzle.
// ---------------------------------------------------------------------------
template<int BM, int BN, int WM, int WN, typename OUT>
__global__ __launch_bounds__(256) void gemm_async(
    const unsigned short* __restrict__ A, const unsigned short* __restrict__ Bw,
    const float* __restrict__ bias, OUT* __restrict__ C,
    int M, int N, int K)
{
  constexpr int BK = 64;
  __shared__ __align__(16) unsigned short lA[BM * BK];
  __shared__ __align__(16) unsigned short lB[BN * BK];
  const int tid = threadIdx.x;
  const int lane = tid & 63;
  const int wv = tid >> 6;
  const int q = lane >> 4, lr = lane & 15;
  const int x7 = lr & 7;
  constexpr int WN_CNT = BN / WN;
  const int wm = (wv / WN_CNT) * WM;
  const int wn = (wv % WN_CNT) * WN;
  const size_t m0 = (size_t)blockIdx.x * BM;
  const size_t n0 = (size_t)blockIdx.y * BN;
  constexpr int MI = WM / 16, NI = WN / 16;
  f32x4 acc[MI][NI] = {};
  constexpr int A_INSTR = BM * BK / 512;   // 1024B DMA instructions
  constexpr int B_INSTR = BN * BK / 512;
  constexpr int A_PW = A_INSTR / 4, B_PW = B_INSTR / 4;
  (void)M;

  for (int k0 = 0; k0 < K; k0 += BK) {
    __syncthreads();
    #pragma unroll
    for (int s = 0; s < A_PW; ++s) {
      int instr = wv * A_PW + s;
      int pc = instr * 64 + lane;
      int row = pc >> 3, col = pc & 7;
      int lc = col ^ (row & 7);
      gl2lds16(A + (m0 + row) * K + k0 + lc * 8, lA + instr * 512);
    }
    #pragma unroll
    for (int s = 0; s < B_PW; ++s) {
      int instr = wv * B_PW + s;
      int pc = instr * 64 + lane;
      int row = pc >> 3, col = pc & 7;
      int lc = col ^ (row & 7);
      gl2lds16(Bw + (n0 + row) * K + k0 + lc * 8, lB + instr * 512);
    }
    __syncthreads();
    #pragma unroll
    for (int t = 0; t < 2; ++t) {
      short8 af[MI], bfr[NI];
      #pragma unroll
      for (int i = 0; i < MI; ++i) {
        int r = wm + i * 16 + lr;
        af[i] = *(const short8*)(lA + r * 64 + (((t << 2) | q) ^ x7) * 8);
      }
      #pragma unroll
      for (int j = 0; j < NI; ++j) {
        int r = wn + j * 16 + lr;
        bfr[j] = *(const short8*)(lB + r * 64 + (((t << 2) | q) ^ x7) * 8);
      }
      #pragma unroll
      for (int i = 0; i < MI; ++i)
        #pragma unroll
        for (int j = 0; j < NI; ++j)
          acc[i][j] = __builtin_amdgcn_mfma_f32_16x16x32_bf16(af[i], bfr[j], acc[i][j], 0, 0, 0);
    }
  }
  #pragma unroll
  for (int i = 0; i < MI; ++i)
    #pragma unroll
    for (int j = 0; j < NI; ++j) {
      size_t col = n0 + wn + j * 16 + lr;
      float bv = bias[col];
      #pragma unroll
      for (int r = 0; r < 4; ++r) {
        size_t row = m0 + wm + i * 16 + q * 4 + r;
        float v = acc[i][j][r] + bv;
        v = v > 0.f ? v : 0.f;
        if (sizeof(OUT) == 2) ((unsigned short*)C)[row * N + col] = f2bf(v);
        else                  ((float*)C)[row * N + col] = v;
      }
    }
}

// ---------------------------------------------------------------------------
// Precompute (parallel): block 0 -> Ap/Am/b2c; blocks 1..16 -> Qt (TRANSPOSED:
// Qt[w*64+j] so pw_lin's per-lane weight reads are contiguous in j).
// ---------------------------------------------------------------------------
__global__ __launch_bounds__(256) void precompute(
    const float* __restrict__ w0, const float* __restrict__ w1,
    const float* __restrict__ l2W, const float* __restrict__ l2b,
    float2* __restrict__ Ap, float2* __restrict__ Am,
    float2* __restrict__ Qt, float2* __restrict__ b2c)
{
  const int t = threadIdx.x;
  const int blk = blockIdx.x;
  if (blk == 0) {
    if (t < 64) {
      float apx = 0, apy = 0, amx = 0, amy = 0;
      for (int m = 0; m < 32; ++m) {
        float s0 = w0[m * 64 + t];
        float cf = w1[m * 64 + t] * s0;
        float sn, cs; sincosf(PI2F * (float)m / 32.f, &sn, &cs);
        if (s0 > 0.f)      { apx += cs * cf; apy += sn * cf; }
        else if (s0 < 0.f) { amx += cs * cf; amy += sn * cf; }
      }
      Ap[t] = make_float2(apx, apy);
      Am[t] = make_float2(amx, amy);
      float bx = 0, by = 0;
      for (int k = 0; k < 64; ++k) {
        float sn, cs; sincosf(PI2F * (float)((t * k) & 63) / 64.f, &sn, &cs);
        float lb = l2b[k] * (1.f / 64.f);
        bx += cs * lb; by += sn * lb;
      }
      b2c[t] = make_float2(bx, by);
    }
  } else {
    int e = (blk - 1) * 256 + t;
    int j = e >> 6, w = e & 63;
    float qx = 0, qy = 0;
    for (int k = 0; k < 64; ++k) {
      float sn, cs; sincosf(PI2F * (float)((j * k) & 63) / 64.f, &sn, &cs);
      float lw = l2W[k * 64 + w] * (1.f / 64.f);
      qx += cs * lw; qy += sn * lw;
    }
    Qt[w * 64 + j] = make_float2(qx, qy);   // transposed store
  }
}

// ---------------------------------------------------------------------------
// DFT along axis1 (64-pt forward). 1024 blocks x 32 rows; unroll-by-4 with
// broadcast ds_read_b128 of the x tile.
// ---------------------------------------------------------------------------
__global__ __launch_bounds__(256) void dft64_rows(
    const float* __restrict__ x3, float2* __restrict__ xh1)
{
  __shared__ __align__(16) float xt[32][64];
  __shared__ float2 tw[64];
  const int t = threadIdx.x;
  const size_t b0 = (size_t)blockIdx.x * 32;
  for (int it = 0; it < 8; ++it) {
    int idx = it * 256 + t;
    int r = idx >> 6, w = idx & 63;
    xt[r][w] = x3[(b0 + r) * 64 + w];
  }
  if (t < 64) {
    float sn, cs; sincosf(-PI2F * (float)t / 64.f, &sn, &cs);
    tw[t] = make_float2(cs, sn);
  }
  __syncthreads();
  const int k = t & 63, rg = t >> 6;
  float2 acc[8] = {};
  #pragma unroll 1
  for (int w4 = 0; w4 < 16; ++w4) {
    int w = 4 * w4;
    int kw = k * w;
    float2 t0 = tw[kw & 63];
    float2 t1 = tw[(kw + k) & 63];
    float2 t2 = tw[(kw + 2 * k) & 63];
    float2 t3 = tw[(kw + 3 * k) & 63];
    #pragma unroll
    for (int r = 0; r < 8; ++r) {
      float4 xv = *(const float4*)(&xt[rg * 8 + r][w]);
      acc[r].x += xv.x * t0.x + xv.y * t1.x + xv.z * t2.x + xv.w * t3.x;
      acc[r].y += xv.x * t0.y + xv.y * t1.y + xv.z * t2.y + xv.w * t3.y;
    }
  }
  #pragma unroll
  for (int r = 0; r < 8; ++r)
    xh1[(b0 + rg * 8 + r) * 64 + k] = acc[r];
}

// ---------------------------------------------------------------------------
// Batch-axis FFT stage 1: 128-pt DFT over b1 as radix-16 x radix-8, then
// inter-stage twiddle W32768^{b2*k1} (incremental rotation).
// ---------------------------------------------------------------------------
template<int SIGN>
__global__ __launch_bounds__(256) void fft_stage1(
    const float2* __restrict__ Xin, float2* __restrict__ T)
{
  __shared__ float2 tile[128 * 33];
  __shared__ float2 tw16s[16];
  const int blk = blockIdx.x;
  const int b2 = blk >> 1, wh = (blk & 1) * 32;
  const int t = threadIdx.x;
  for (int it = 0; it < 16; ++it) {
    int idx = it * 256 + t;
    int b1 = idx >> 5, wi = idx & 31;
    tile[b1 * 33 + wi] = Xin[((size_t)(b1 * 256 + b2)) * 64 + wh + wi];
  }
  if (t < 16) {
    float sn, cs; sincosf(SIGN * PI2F * (float)t / 16.f, &sn, &cs);
    tw16s[t] = make_float2(cs, sn);
  }
  __syncthreads();
  // ---- phase A: thread -> pair p=t>>1 (n2=p>>4, k1p=p&15), w0=(t&1)*16
  const int p = t >> 1, n2a = p >> 4, k1pa = p & 15, w0 = (t & 1) * 16;
  float2 ya[16] = {};
  #pragma unroll 1
  for (int n1 = 0; n1 < 16; ++n1) {
    float2 tv = tw16s[(n1 * k1pa) & 15];       // LDS broadcast
    const float2* row = &tile[(8 * n1 + n2a) * 33 + w0];
    #pragma unroll
    for (int w = 0; w < 16; ++w) {
      float2 d = row[w];
      ya[w].x += d.x * tv.x - d.y * tv.y;
      ya[w].y += d.x * tv.y + d.y * tv.x;
    }
  }
  {
    float sn, cs; sincosf(SIGN * PI2F * (float)(n2a * k1pa) / 128.f, &sn, &cs);
    #pragma unroll
    for (int w = 0; w < 16; ++w) {
      float2 a = ya[w];
      ya[w] = make_float2(a.x * cs - a.y * sn, a.x * sn + a.y * cs);
    }
  }
  __syncthreads();                       // all phase-A reads of tile done
  {
    float2* yrow = &tile[(n2a * 16 + k1pa) * 33 + w0];
    #pragma unroll
    for (int w = 0; w < 16; ++w) yrow[w] = ya[w];
  }
  __syncthreads();                       // y visible
  // ---- phase B: thread -> (w = t&31, q = t>>5); k1p in {q, q+8}
  const int wB = t & 31, qB = t >> 5;
  float sstep, cstep;
  sincosf(SIGN * PI2F * (float)(16 * b2) / 32768.f, &sstep, &cstep);
  #pragma unroll 1
  for (int h = 0; h < 2; ++h) {
    const int k1p = qB + 8 * h;
    float2 acc[8] = {};
    #pragma unroll 1
    for (int n2 = 0; n2 < 8; ++n2) {
      float2 d = tile[(n2 * 16 + k1p) * 33 + wB];
      #pragma unroll
      for (int k2p = 0; k2p < 8; ++k2p) {
        float2 tv = tw16s[(2 * n2 * k2p) & 15];  // W8^{n2 k2p}, LDS broadcast
        acc[k2p].x += d.x * tv.x - d.y * tv.y;
        acc[k2p].y += d.x * tv.y + d.y * tv.x;
      }
    }
    float sb, cb;
    sincosf(SIGN * PI2F * (float)(b2 * k1p) / 32768.f, &sb, &cb);
    float2 rot = make_float2(cb, sb);
    #pragma unroll
    for (int k2p = 0; k2p < 8; ++k2p) {
      int k1 = k1p + 16 * k2p;
      float2 a = acc[k2p];
      float2 o = make_float2(a.x * rot.x - a.y * rot.y,
                             a.x * rot.y + a.y * rot.x);
      T[((size_t)k1 * 256 + b2) * 64 + wh + wB] = o;
      float nrx = rot.x * cstep - rot.y * sstep;
      rot.y = rot.x * sstep + rot.y * cstep;
      rot.x = nrx;
    }
  }
}

// ---------------------------------------------------------------------------
// Batch-axis FFT stage 2: 256-pt DFT over b2 as radix-16 x radix-16.
// ---------------------------------------------------------------------------
template<int SIGN, bool SCALE>
__global__ __launch_bounds__(256) void fft_stage2(
    const float2* __restrict__ T, float2* __restrict__ X)
{
  __shared__ float2 tile[256 * 17];
  __shared__ float2 tw16s[16];
  const int blk = blockIdx.x;
  const int k1 = blk >> 2, wq = (blk & 3) * 16;
  const int t = threadIdx.x;
  for (int it = 0; it < 16; ++it) {
    int idx = it * 256 + t;
    int r2 = idx >> 4, wi = idx & 15;
    tile[r2 * 17 + wi] = T[((size_t)k1 * 256 + r2) * 64 + wq + wi];
  }
  if (t < 16) {
    float sn, cs; sincosf(SIGN * PI2F * (float)t / 16.f, &sn, &cs);
    tw16s[t] = make_float2(cs, sn);
  }
  __syncthreads();
  // ---- phase A: thread -> (n2 = t>>4, k1p = t&15)
  const int n2a = t >> 4, k1pa = t & 15;
  float2 ya[16] = {};
  #pragma unroll 1
  for (int n1 = 0; n1 < 16; ++n1) {
    float2 tv = tw16s[(n1 * k1pa) & 15];       // LDS broadcast
    const float2* row = &tile[(16 * n1 + n2a) * 17];
    #pragma unroll
    for (int w = 0; w < 16; ++w) {
      float2 d = row[w];
      ya[w].x += d.x * tv.x - d.y * tv.y;
      ya[w].y += d.x * tv.y + d.y * tv.x;
    }
  }
  {
    float sn, cs; sincosf(SIGN * PI2F * (float)(n2a * k1pa) / 256.f, &sn, &cs);
    #pragma unroll
    for (int w = 0; w < 16; ++w) {
      float2 a = ya[w];
      ya[w] = make_float2(a.x * cs - a.y * sn, a.x * sn + a.y * cs);
    }
  }
  __syncthreads();                       // all phase-A reads done
  {
    float2* yrow = &tile[(n2a * 16 + k1pa) * 17];
    #pragma unroll
    for (int w = 0; w < 16; ++w) yrow[w] = ya[w];
  }
  __syncthreads();                       // y visible
  // ---- phase B: thread -> (k1p = t>>4, w = t&15)
  const int k1pb = t >> 4, wB = t & 15;
  float2 acc[16] = {};
  #pragma unroll 1
  for (int n2 = 0; n2 < 16; ++n2) {
    float2 d = tile[(n2 * 16 + k1pb) * 17 + wB];
    #pragma unroll
    for (int k2p = 0; k2p < 16; ++k2p) {
      float2 tv = tw16s[(n2 * k2p) & 15];      // LDS broadcast
      acc[k2p].x += d.x * tv.x - d.y * tv.y;
      acc[k2p].y += d.x * tv.y + d.y * tv.x;
    }
  }
  const float sc = SCALE ? (1.f / 32768.f) : 1.f;
  #pragma unroll
  for (int k2p = 0; k2p < 16; ++k2p) {
    int k2 = k1pb + 16 * k2p;
    size_t row = (size_t)(k1 + 128 * k2);
    X[row * 64 + wq + wB] = make_float2(acc[k2p].x * sc, acc[k2p].y * sc);
  }
}

// ---------------------------------------------------------------------------
// Pointwise A+/- fold, lin1 crelu, Q-fold (ifft64+lin2).
// R10: one in-place 16KB y/z tile (wave-private rows), Qt staged in LDS via
// DMA (conflict-free per-lane b64 weight reads), unroll-by-4 broadcast b128
// tile reads, rolling 1-ahead l1W prefetch. Single barrier.
// ---------------------------------------------------------------------------
__global__ __launch_bounds__(256) void pw_lin(
    const float2* __restrict__ xh,
    const float2* __restrict__ Ap, const float2* __restrict__ Am,
    const float* __restrict__ l1W, const float* __restrict__ l1b,
    const float2* __restrict__ Qt, const float2* __restrict__ b2c,
    float2* __restrict__ u)
{
  __shared__ __align__(16) float2 tile[32][64];   // y, then z in place
  __shared__ __align__(16) float2 qt[64 * 64];    // Qt[w][j], 32KB
  const int t = threadIdx.x;
  const int lane = t & 63;
  const int wv = t >> 6;
  const size_t b0 = (size_t)blockIdx.x * 32;

  // stage Qt (32KB) via async DMA: 32 x 1KB instrs, 8 per wave
  #pragma unroll
  for (int s = 0; s < 8; ++s) {
    int instr = wv * 8 + s;
    gl2lds16((const char*)Qt + instr * 1024 + lane * 16,
             (const char*)qt + instr * 1024);
  }

  // phase 0: pointwise A+/- fold -> y
  for (int it = 0; it < 8; ++it) {
    int idx = it * 256 + t;
    int r = idx >> 6, w = idx & 63;
    float2 xv = xh[(b0 + r) * 64 + w];
    float2 Aa = (xv.x >= 0.f) ? Ap[w] : Am[w];
    float2 Ab = (xv.y >= 0.f) ? Ap[w] : Am[w];
    tile[r][w] = make_float2(xv.x * Aa.x - xv.y * Ab.y,
                             xv.x * Aa.y + xv.y * Ab.x);
  }
  __syncthreads();   // y visible to all waves; Qt DMA drained (vmcnt0)

  const int n = lane, rg = wv;   // wave rg owns tile rows [8rg, 8rg+8)

  // lin1: z[r][n] = crelu(sum_w y[r][w] * l1W[n][w] + b[n]); in place.
  // Reads+writes touch only this wave's 8 rows -> no barrier needed.
  {
    float2 acc[8] = {};
    const float* wrow = l1W + n * 64;
    float4 lwn = *(const float4*)wrow;             // rolling prefetch
    #pragma unroll 1
    for (int w2 = 0; w2 < 16; ++w2) {
      float4 lw = lwn;
      lwn = *(const float4*)(wrow + 4 * ((w2 + 1) & 15));
      int w = 4 * w2;
      #pragma unroll
      for (int r = 0; r < 8; ++r) {
        const float4* rowp = (const float4*)(&tile[rg * 8 + r][w]);
        float4 y01 = rowp[0];                      // broadcast b128
        float4 y23 = rowp[1];
        acc[r].x += y01.x * lw.x + y01.z * lw.y + y23.x * lw.z + y23.z * lw.w;
        acc[r].y += y01.y * lw.x + y01.w * lw.y + y23.y * lw.z + y23.w * lw.w;
      }
    }
    float bb = l1b[n];
    #pragma unroll
    for (int r = 0; r < 8; ++r) {
      float zr = acc[r].x + bb; zr = zr > 0.f ? zr : 0.f;
      float zi = acc[r].y;      zi = zi > 0.f ? zi : 0.f;
      tile[rg * 8 + r][n] = make_float2(zr, zi);   // same-wave rows only
    }
  }

  // Q-fold: u[r][j] = sum_w z[r][w] * Qt[w][j] + b2c[j]
  {
    const int j = lane;
    float2 acc[8] = {};
    #pragma unroll 1
    for (int w2 = 0; w2 < 16; ++w2) {
      int w = 4 * w2;
      float2 q0 = qt[(w + 0) * 64 + j];            // contiguous per-lane b64
      float2 q1 = qt[(w + 1) * 64 + j];
      float2 q2 = qt[(w + 2) * 64 + j];
      float2 q3 = qt[(w + 3) * 64 + j];
      #pragma unroll
      for (int r = 0; r < 8; ++r) {
        const float4* rowp = (const float4*)(&tile[rg * 8 + r][w]);
        float4 z01 = rowp[0];                      // broadcast b128
        float4 z23 = rowp[1];
        acc[r].x += z01.x * q0.x - z01.y * q0.y
                  + z01.z * q1.x - z01.w * q1.y
                  + z23.x * q2.x - z23.y * q2.y
                  + z23.z * q3.x - z23.w * q3.y;
        acc[r].y += z01.x * q0.y + z01.y * q0.x
                  + z01.z * q1.y + z01.w * q1.x
                  + z23.x * q2.y + z23.y * q2.x
                  + z23.z * q3.y + z23.w * q3.x;
      }
    }
    float2 bc = b2c[j];
    #pragma unroll
    for (int r = 0; r < 8; ++r)
      u[(b0 + rg * 8 + r) * 64 + j] = make_float2(acc[r].x + bc.x, acc[r].y + bc.y);
  }
}

// ---------------------------------------------------------------------------
// Final W_out GEMM; MODE 0 = real only, MODE 1 = interleaved (re,im).
// R10: 1024 blocks x 32 rows, unroll-by-2 broadcast b128 reads, rolling
// Wout prefetch.
// ---------------------------------------------------------------------------
template<int MODE>
__global__ __launch_bounds__(256) void final_out(
    const float2* __restrict__ v, const float* __restrict__ Wout,
    const float* __restrict__ bout, float* __restrict__ out)
{
  __shared__ __align__(16) float2 vt[32][64];
  const int t = threadIdx.x;
  const size_t b0 = (size_t)blockIdx.x * 32;
  for (int it = 0; it < 8; ++it) {
    int idx = it * 256 + t;
    int r = idx >> 6, w = idx & 63;
    vt[r][w] = v[(b0 + r) * 64 + w];
  }
  __syncthreads();
  const int f = t & 127, rg = t >> 7;
  const float* wrow = Wout + f * 64;
  float2 acc[16] = {};
  float2 wvn = *(const float2*)wrow;               // rolling prefetch
  #pragma unroll 1
  for (int j2 = 0; j2 < 32; ++j2) {
    float2 wc = wvn;
    wvn = *(const float2*)(wrow + 2 * ((j2 + 1) & 31));
    #pragma unroll
    for (int r = 0; r < 16; ++r) {
      float4 vv = *(const float4*)(&vt[rg * 16 + r][2 * j2]);  // broadcast b128
      acc[r].x += vv.x * wc.x + vv.z * wc.y;
      acc[r].y += vv.y * wc.x + vv.w * wc.y;
    }
  }
  float bb = bout[f];
  #pragma unroll
  for (int r = 0; r < 16; ++r) {
    size_t idx = (b0 + rg * 16 + r) * 128 + f;
    if (MODE == 0) out[idx] = acc[r].x + bb;
    else ((float2*)out)[idx] = make_float2(acc[r].x + bb, acc[r].y);
  }
}

// ---------------------------------------------------------------------------
extern "C" void kernel_launch(void* const* d_in, const int* in_sizes, int n_in,
                              void* d_out, int out_size, void* d_ws, size_t ws_size,
                              hipStream_t stream)
{
  (void)in_sizes; (void)n_in; (void)ws_size;
  const float* geom = (const float*)d_in[0];
  const float* Win  = (const float*)d_in[1];
  const float* bin  = (const float*)d_in[2];
  const float* Wh1  = (const float*)d_in[3];
  const float* bh1  = (const float*)d_in[4];
  const float* Wh2  = (const float*)d_in[5];
  const float* bh2  = (const float*)d_in[6];
  const float* w0   = (const float*)d_in[7];
  const float* w1   = (const float*)d_in[8];
  const float* l1W  = (const float*)d_in[9];
  const float* l1b  = (const float*)d_in[10];
  const float* l2W  = (const float*)d_in[11];
  const float* l2b  = (const float*)d_in[12];
  const float* Wout = (const float*)d_in[13];
  const float* bout = (const float*)d_in[14];

  char* ws = (char*)d_ws;
  const size_t MB = 1048576ull;
  unsigned short* geomb = (unsigned short*)(ws);
  unsigned short* x2b   = (unsigned short*)(ws);
  unsigned short* x1b   = (unsigned short*)(ws + 32 * MB);
  float*  x3  = (float*)(ws + 32 * MB);
  float2* S0  = (float2*)(ws + 40 * MB);
  float2* S1  = (float2*)(ws + 56 * MB);
  float2* Ap  = (float2*)(ws + 72 * MB);
  float2* Am  = (float2*)(ws + 72 * MB + 512);
  float2* b2c = (float2*)(ws + 72 * MB + 1024);
  float2* Qt  = (float2*)(ws + 72 * MB + 1536);
  unsigned short* Winb = (unsigned short*)(ws + 96 * MB);
  unsigned short* Wh1b = (unsigned short*)(ws + 97 * MB);
  unsigned short* Wh2b = (unsigned short*)(ws + 98 * MB);

  f32_to_bf16_k<<<16384, 256, 0, stream>>>(geom, geomb, 4194304);
  f32_to_bf16_k<<<512, 256, 0, stream>>>(Win, Winb, 131072);
  f32_to_bf16_k<<<512, 256, 0, stream>>>(Wh1, Wh1b, 131072);
  f32_to_bf16_k<<<32, 256, 0, stream>>>(Wh2, Wh2b, 8192);

  gemm_async<128,128,64,64,unsigned short><<<dim3(256, 8), 256, 0, stream>>>(
      geomb, Winb, bin, x1b, 32768, 1024, 512);
  gemm_async<128,128,64,64,unsigned short><<<dim3(256, 4), 256, 0, stream>>>(
      x1b, Wh1b, bh1, x2b, 32768, 512, 1024);
  gemm_async<128, 64,64,32,float><<<dim3(256, 1), 256, 0, stream>>>(
      x2b, Wh2b, bh2, x3, 32768, 64, 512);

  precompute<<<17, 256, 0, stream>>>(w0, w1, l2W, l2b, Ap, Am, Qt, b2c);
  dft64_rows<<<1024, 256, 0, stream>>>(x3, S0);
  fft_stage1<-1><<<512, 256, 0, stream>>>(S0, S1);
  fft_stage2<-1, false><<<512, 256, 0, stream>>>(S1, S0);
  pw_lin<<<1024, 256, 0, stream>>>(S0, Ap, Am, l1W, l1b, Qt, b2c, S1);
  fft_stage1<1><<<512, 256, 0, stream>>>(S1, S0);
  fft_stage2<1, true><<<512, 256, 0, stream>>>(S0, S1);
  if (out_size >= 8388608) {
    final_out<1><<<1024, 256, 0, stream>>>(S1, Wout, bout, (float*)d_out);
  } else {
    final_out<0><<<1024, 256, 0, stream>>>(S1, Wout, bout, (float*)d_out);
  }
}

// Round 2
// 436.603 us; speedup vs baseline: 1.0961x; 1.0312x over previous
//
#include <hip/hip_runtime.h>
#include <hip/hip_bf16.h>

// ---------------------------------------------------------------------------
// FieldPredictionNetwork. R11: the two big encoder GEMMs (61us each, MfmaUtil
// 22%) are stage-serialized: 128^2 single-buffer stages 32KB/k-step through a
// full vmcnt(0) barrier drain with only ~154cy of MFMA wall-time to hide it,
// and ~1.5 blocks/CU resident. Rewrite GEMM1/2 as 256^2-tile 8-wave BK=64
// DOUBLE-BUFFERED 2-phase (128KB LDS): stage(t+1) issued before compute(t),
// one syncthreads per k-step. 512 MFMA/block/k-step (614cy) vs 64KB stage
// (~1100cy) -> ~2.5x better duty cycle, and L2 staging traffic halves
// (256MB vs 512MB per GEMM). Same proven XOR-swizzle layout + fragment
// mapping. setprio(1) around MFMA cluster. GEMM3 + all FFT/pointwise
// kernels untouched from R10.
// ---------------------------------------------------------------------------

#define PI2F 6.28318530717958647692f

typedef __attribute__((ext_vector_type(8))) short short8;
typedef __attribute__((ext_vector_type(4))) float f32x4;

__device__ __forceinline__ unsigned short f2bf(float f) {
  unsigned int u = __float_as_uint(f);
  u += 0x7fff + ((u >> 16) & 1);          // RN-even
  return (unsigned short)(u >> 16);
}
__device__ __forceinline__ unsigned int pack_bf16x2(float a, float b) {
  return (unsigned int)f2bf(a) | ((unsigned int)f2bf(b) << 16);
}

// async 16B global->LDS DMA; lds dest must be wave-uniform (HW adds lane*16)
__device__ __forceinline__ void gl2lds16(const void* gptr, const void* lptr) {
  __builtin_amdgcn_global_load_lds(
      (const __attribute__((address_space(1))) unsigned int*)(unsigned long long)gptr,
      (__attribute__((address_space(3))) unsigned int*)(unsigned int)(unsigned long long)lptr,
      16, 0, 0);
}

// ---------------------------------------------------------------------------
// f32 -> bf16 pack (4 elems/thread)
// ---------------------------------------------------------------------------
__global__ __launch_bounds__(256) void f32_to_bf16_k(
    const float* __restrict__ src, unsigned short* __restrict__ dst, int n4)
{
  int i = blockIdx.x * 256 + threadIdx.x;
  if (i < n4) {
    float4 v = ((const float4*)src)[i];
    uint2 p;
    p.x = pack_bf16x2(v.x, v.y);
    p.y = pack_bf16x2(v.z, v.w);
    ((uint2*)dst)[i] = p;
  }
}

// ---------------------------------------------------------------------------
// R11: 256x256-tile 8-wave double-buffered GEMM: C = relu(A @ Bw^T + bias).
// A [M,K] bf16, Bw [N,K] bf16, bias f32. BK=64, 2-phase pipeline:
//   STAGE(buf0); sync; loop{ STAGE(buf^1,t+1); COMPUTE(buf); sync; }
// 128KB LDS (dbuf), 1 block/CU, wave grid 2(M)x4(N), per-wave 128x64 out.
// ---------------------------------------------------------------------------
template<typename OUT>
__global__ __launch_bounds__(512, 2) void gemm256_db(
    const unsigned short* __restrict__ A, const unsigned short* __restrict__ Bw,
    const float* __restrict__ bias, OUT* __restrict__ C,
    int N, int K)
{
  constexpr int BM = 256, BN = 256, BK = 64;
  __shared__ __align__(16) unsigned short lds[2 * (BM + BN) * BK];  // 128 KB
  const int tid = threadIdx.x;
  const int lane = tid & 63;
  const int wv = tid >> 6;
  const int q = lane >> 4, lr = lane & 15;
  const int x7 = lr & 7;
  const int wm = (wv >> 2) * 128;          // 2 wave-rows
  const int wn = (wv & 3) * 64;            // 4 wave-cols
  const size_t m0 = (size_t)blockIdx.x * BM;
  const size_t n0 = (size_t)blockIdx.y * BN;
  constexpr int MI = 8, NI = 4;            // per-wave 128x64 output
  f32x4 acc[MI][NI] = {};

  // stage one k-step (A 32KB + B 32KB) into buffer c; 8 DMA instrs per wave
  auto STAGE = [&](int c, int kk) {
    unsigned short* dA = lds + c * (BM + BN) * BK;
    unsigned short* dB = dA + BM * BK;
    #pragma unroll
    for (int s = 0; s < 4; ++s) {
      int instr = wv * 4 + s;
      int pc = instr * 64 + lane;
      int row = pc >> 3, col = pc & 7;
      int lc = col ^ (row & 7);
      gl2lds16(A + (m0 + row) * (size_t)K + kk + lc * 8, dA + instr * 512);
    }
    #pragma unroll
    for (int s = 0; s < 4; ++s) {
      int instr = wv * 4 + s;
      int pc = instr * 64 + lane;
      int row = pc >> 3, col = pc & 7;
      int lc = col ^ (row & 7);
      gl2lds16(Bw + (n0 + row) * (size_t)K + kk + lc * 8, dB + instr * 512);
    }
  };

  auto COMPUTE = [&](int c) {
    const unsigned short* sA = lds + c * (BM + BN) * BK;
    const unsigned short* sB = sA + BM * BK;
    #pragma unroll
    for (int t2 = 0; t2 < 2; ++t2) {
      short8 af[MI], bfr[NI];
      #pragma unroll
      for (int i = 0; i < MI; ++i) {
        int r = wm + i * 16 + lr;
        af[i] = *(const short8*)(sA + r * 64 + (((t2 << 2) | q) ^ x7) * 8);
      }
      #pragma unroll
      for (int j = 0; j < NI; ++j) {
        int r = wn + j * 16 + lr;
        bfr[j] = *(const short8*)(sB + r * 64 + (((t2 << 2) | q) ^ x7) * 8);
      }
      __builtin_amdgcn_s_setprio(1);
      #pragma unroll
      for (int i = 0; i < MI; ++i)
        #pragma unroll
        for (int j = 0; j < NI; ++j)
          acc[i][j] = __builtin_amdgcn_mfma_f32_16x16x32_bf16(af[i], bfr[j], acc[i][j], 0, 0, 0);
      __builtin_amdgcn_s_setprio(0);
    }
  };

  const int nt = K / BK;
  STAGE(0, 0);
  __syncthreads();                         // vmcnt(0) drain + barrier
  for (int t = 0; t < nt; ++t) {
    int cur = t & 1;
    if (t + 1 < nt) STAGE(cur ^ 1, (t + 1) * BK);  // issue next-tile DMA
    COMPUTE(cur);                                   // overlaps with DMA
    __syncthreads();                         // drain own stage + reads done
  }

  #pragma unroll
  for (int i = 0; i < MI; ++i)
    #pragma unroll
    for (int j = 0; j < NI; ++j) {
      size_t col = n0 + wn + j * 16 + lr;
      float bv = bias[col];
      #pragma unroll
      for (int r = 0; r < 4; ++r) {
        size_t row = m0 + wm + i * 16 + q * 4 + r;
        float v = acc[i][j][r] + bv;
        v = v > 0.f ? v : 0.f;
        if (sizeof(OUT) == 2) ((unsigned short*)C)[row * N + col] = f2bf(v);
        else                  ((float*)C)[row * N + col] = v;
      }
    }
}

// ---------------------------------------------------------------------------
// GEMM (legacy 128-tile, used for GEMM3 only): C = relu(A @ Bw^T + bias).
// ---------------------------------------------------------------------------
template<int BM, int BN, int WM, int WN, typename OUT>
__global__ __launch_bounds__(256) void gemm_async(
    const unsigned short* __restrict__ A, const unsigned short* __restrict__ Bw,
    const float* __restrict__ bias, OUT* __restrict__ C,
    int M, int N, int K)
{
  constexpr int BK = 64;
  __shared__ __align__(16) unsigned short lA[BM * BK];
  __shared__ __align__(16) unsigned short lB[BN * BK];
  const int tid = threadIdx.x;
  const int lane = tid & 63;
  const int wv = tid >> 6;
  const int q = lane >> 4, lr = lane & 15;
  const int x7 = lr & 7;
  constexpr int WN_CNT = BN / WN;
  const int wm = (wv / WN_CNT) * WM;
  const int wn = (wv % WN_CNT) * WN;
  const size_t m0 = (size_t)blockIdx.x * BM;
  const size_t n0 = (size_t)blockIdx.y * BN;
  constexpr int MI = WM / 16, NI = WN / 16;
  f32x4 acc[MI][NI] = {};
  constexpr int A_INSTR = BM * BK / 512;   // 1024B DMA instructions
  constexpr int B_INSTR = BN * BK / 512;
  constexpr int A_PW = A_INSTR / 4, B_PW = B_INSTR / 4;
  (void)M;

  for (int k0 = 0; k0 < K; k0 += BK) {
    __syncthreads();
    #pragma unroll
    for (int s = 0; s < A_PW; ++s) {
      int instr = wv * A_PW + s;
      int pc = instr * 64 + lane;
      int row = pc >> 3, col = pc & 7;
      int lc = col ^ (row & 7);
      gl2lds16(A + (m0 + row) * K + k0 + lc * 8, lA + instr * 512);
    }
    #pragma unroll
    for (int s = 0; s < B_PW; ++s) {
      int instr = wv * B_PW + s;
      int pc = instr * 64 + lane;
      int row = pc >> 3, col = pc & 7;
      int lc = col ^ (row & 7);
      gl2lds16(Bw + (n0 + row) * K + k0 + lc * 8, lB + instr * 512);
    }
    __syncthreads();
    #pragma unroll
    for (int t = 0; t < 2; ++t) {
      short8 af[MI], bfr[NI];
      #pragma unroll
      for (int i = 0; i < MI; ++i) {
        int r = wm + i * 16 + lr;
        af[i] = *(const short8*)(lA + r * 64 + (((t << 2) | q) ^ x7) * 8);
      }
      #pragma unroll
      for (int j = 0; j < NI; ++j) {
        int r = wn + j * 16 + lr;
        bfr[j] = *(const short8*)(lB + r * 64 + (((t << 2) | q) ^ x7) * 8);
      }
      #pragma unroll
      for (int i = 0; i < MI; ++i)
        #pragma unroll
        for (int j = 0; j < NI; ++j)
          acc[i][j] = __builtin_amdgcn_mfma_f32_16x16x32_bf16(af[i], bfr[j], acc[i][j], 0, 0, 0);
    }
  }
  #pragma unroll
  for (int i = 0; i < MI; ++i)
    #pragma unroll
    for (int j = 0; j < NI; ++j) {
      size_t col = n0 + wn + j * 16 + lr;
      float bv = bias[col];
      #pragma unroll
      for (int r = 0; r < 4; ++r) {
        size_t row = m0 + wm + i * 16 + q * 4 + r;
        float v = acc[i][j][r] + bv;
        v = v > 0.f ? v : 0.f;
        if (sizeof(OUT) == 2) ((unsigned short*)C)[row * N + col] = f2bf(v);
        else                  ((float*)C)[row * N + col] = v;
      }
    }
}

// ---------------------------------------------------------------------------
// Precompute (parallel): block 0 -> Ap/Am/b2c; blocks 1..16 -> Qt (TRANSPOSED:
// Qt[w*64+j] so pw_lin's per-lane weight reads are contiguous in j).
// ---------------------------------------------------------------------------
__global__ __launch_bounds__(256) void precompute(
    const float* __restrict__ w0, const float* __restrict__ w1,
    const float* __restrict__ l2W, const float* __restrict__ l2b,
    float2* __restrict__ Ap, float2* __restrict__ Am,
    float2* __restrict__ Qt, float2* __restrict__ b2c)
{
  const int t = threadIdx.x;
  const int blk = blockIdx.x;
  if (blk == 0) {
    if (t < 64) {
      float apx = 0, apy = 0, amx = 0, amy = 0;
      for (int m = 0; m < 32; ++m) {
        float s0 = w0[m * 64 + t];
        float cf = w1[m * 64 + t] * s0;
        float sn, cs; sincosf(PI2F * (float)m / 32.f, &sn, &cs);
        if (s0 > 0.f)      { apx += cs * cf; apy += sn * cf; }
        else if (s0 < 0.f) { amx += cs * cf; amy += sn * cf; }
      }
      Ap[t] = make_float2(apx, apy);
      Am[t] = make_float2(amx, amy);
      float bx = 0, by = 0;
      for (int k = 0; k < 64; ++k) {
        float sn, cs; sincosf(PI2F * (float)((t * k) & 63) / 64.f, &sn, &cs);
        float lb = l2b[k] * (1.f / 64.f);
        bx += cs * lb; by += sn * lb;
      }
      b2c[t] = make_float2(bx, by);
    }
  } else {
    int e = (blk - 1) * 256 + t;
    int j = e >> 6, w = e & 63;
    float qx = 0, qy = 0;
    for (int k = 0; k < 64; ++k) {
      float sn, cs; sincosf(PI2F * (float)((j * k) & 63) / 64.f, &sn, &cs);
      float lw = l2W[k * 64 + w] * (1.f / 64.f);
      qx += cs * lw; qy += sn * lw;
    }
    Qt[w * 64 + j] = make_float2(qx, qy);   // transposed store
  }
}

// ---------------------------------------------------------------------------
// DFT along axis1 (64-pt forward). 1024 blocks x 32 rows; unroll-by-4 with
// broadcast ds_read_b128 of the x tile.
// ---------------------------------------------------------------------------
__global__ __launch_bounds__(256) void dft64_rows(
    const float* __restrict__ x3, float2* __restrict__ xh1)
{
  __shared__ __align__(16) float xt[32][64];
  __shared__ float2 tw[64];
  const int t = threadIdx.x;
  const size_t b0 = (size_t)blockIdx.x * 32;
  for (int it = 0; it < 8; ++it) {
    int idx = it * 256 + t;
    int r = idx >> 6, w = idx & 63;
    xt[r][w] = x3[(b0 + r) * 64 + w];
  }
  if (t < 64) {
    float sn, cs; sincosf(-PI2F * (float)t / 64.f, &sn, &cs);
    tw[t] = make_float2(cs, sn);
  }
  __syncthreads();
  const int k = t & 63, rg = t >> 6;
  float2 acc[8] = {};
  #pragma unroll 1
  for (int w4 = 0; w4 < 16; ++w4) {
    int w = 4 * w4;
    int kw = k * w;
    float2 t0 = tw[kw & 63];
    float2 t1 = tw[(kw + k) & 63];
    float2 t2 = tw[(kw + 2 * k) & 63];
    float2 t3 = tw[(kw + 3 * k) & 63];
    #pragma unroll
    for (int r = 0; r < 8; ++r) {
      float4 xv = *(const float4*)(&xt[rg * 8 + r][w]);
      acc[r].x += xv.x * t0.x + xv.y * t1.x + xv.z * t2.x + xv.w * t3.x;
      acc[r].y += xv.x * t0.y + xv.y * t1.y + xv.z * t2.y + xv.w * t3.y;
    }
  }
  #pragma unroll
  for (int r = 0; r < 8; ++r)
    xh1[(b0 + rg * 8 + r) * 64 + k] = acc[r];
}

// ---------------------------------------------------------------------------
// Batch-axis FFT stage 1: 128-pt DFT over b1 as radix-16 x radix-8, then
// inter-stage twiddle W32768^{b2*k1} (incremental rotation).
// ---------------------------------------------------------------------------
template<int SIGN>
__global__ __launch_bounds__(256) void fft_stage1(
    const float2* __restrict__ Xin, float2* __restrict__ T)
{
  __shared__ float2 tile[128 * 33];
  __shared__ float2 tw16s[16];
  const int blk = blockIdx.x;
  const int b2 = blk >> 1, wh = (blk & 1) * 32;
  const int t = threadIdx.x;
  for (int it = 0; it < 16; ++it) {
    int idx = it * 256 + t;
    int b1 = idx >> 5, wi = idx & 31;
    tile[b1 * 33 + wi] = Xin[((size_t)(b1 * 256 + b2)) * 64 + wh + wi];
  }
  if (t < 16) {
    float sn, cs; sincosf(SIGN * PI2F * (float)t / 16.f, &sn, &cs);
    tw16s[t] = make_float2(cs, sn);
  }
  __syncthreads();
  // ---- phase A: thread -> pair p=t>>1 (n2=p>>4, k1p=p&15), w0=(t&1)*16
  const int p = t >> 1, n2a = p >> 4, k1pa = p & 15, w0 = (t & 1) * 16;
  float2 ya[16] = {};
  #pragma unroll 1
  for (int n1 = 0; n1 < 16; ++n1) {
    float2 tv = tw16s[(n1 * k1pa) & 15];       // LDS broadcast
    const float2* row = &tile[(8 * n1 + n2a) * 33 + w0];
    #pragma unroll
    for (int w = 0; w < 16; ++w) {
      float2 d = row[w];
      ya[w].x += d.x * tv.x - d.y * tv.y;
      ya[w].y += d.x * tv.y + d.y * tv.x;
    }
  }
  {
    float sn, cs; sincosf(SIGN * PI2F * (float)(n2a * k1pa) / 128.f, &sn, &cs);
    #pragma unroll
    for (int w = 0; w < 16; ++w) {
      float2 a = ya[w];
      ya[w] = make_float2(a.x * cs - a.y * sn, a.x * sn + a.y * cs);
    }
  }
  __syncthreads();                       // all phase-A reads of tile done
  {
    float2* yrow = &tile[(n2a * 16 + k1pa) * 33 + w0];
    #pragma unroll
    for (int w = 0; w < 16; ++w) yrow[w] = ya[w];
  }
  __syncthreads();                       // y visible
  // ---- phase B: thread -> (w = t&31, q = t>>5); k1p in {q, q+8}
  const int wB = t & 31, qB = t >> 5;
  float sstep, cstep;
  sincosf(SIGN * PI2F * (float)(16 * b2) / 32768.f, &sstep, &cstep);
  #pragma unroll 1
  for (int h = 0; h < 2; ++h) {
    const int k1p = qB + 8 * h;
    float2 acc[8] = {};
    #pragma unroll 1
    for (int n2 = 0; n2 < 8; ++n2) {
      float2 d = tile[(n2 * 16 + k1p) * 33 + wB];
      #pragma unroll
      for (int k2p = 0; k2p < 8; ++k2p) {
        float2 tv = tw16s[(2 * n2 * k2p) & 15];  // W8^{n2 k2p}, LDS broadcast
        acc[k2p].x += d.x * tv.x - d.y * tv.y;
        acc[k2p].y += d.x * tv.y + d.y * tv.x;
      }
    }
    float sb, cb;
    sincosf(SIGN * PI2F * (float)(b2 * k1p) / 32768.f, &sb, &cb);
    float2 rot = make_float2(cb, sb);
    #pragma unroll
    for (int k2p = 0; k2p < 8; ++k2p) {
      int k1 = k1p + 16 * k2p;
      float2 a = acc[k2p];
      float2 o = make_float2(a.x * rot.x - a.y * rot.y,
                             a.x * rot.y + a.y * rot.x);
      T[((size_t)k1 * 256 + b2) * 64 + wh + wB] = o;
      float nrx = rot.x * cstep - rot.y * sstep;
      rot.y = rot.x * sstep + rot.y * cstep;
      rot.x = nrx;
    }
  }
}

// ---------------------------------------------------------------------------
// Batch-axis FFT stage 2: 256-pt DFT over b2 as radix-16 x radix-16.
// ---------------------------------------------------------------------------
template<int SIGN, bool SCALE>
__global__ __launch_bounds__(256) void fft_stage2(
    const float2* __restrict__ T, float2* __restrict__ X)
{
  __shared__ float2 tile[256 * 17];
  __shared__ float2 tw16s[16];
  const int blk = blockIdx.x;
  const int k1 = blk >> 2, wq = (blk & 3) * 16;
  const int t = threadIdx.x;
  for (int it = 0; it < 16; ++it) {
    int idx = it * 256 + t;
    int r2 = idx >> 4, wi = idx & 15;
    tile[r2 * 17 + wi] = T[((size_t)k1 * 256 + r2) * 64 + wq + wi];
  }
  if (t < 16) {
    float sn, cs; sincosf(SIGN * PI2F * (float)t / 16.f, &sn, &cs);
    tw16s[t] = make_float2(cs, sn);
  }
  __syncthreads();
  // ---- phase A: thread -> (n2 = t>>4, k1p = t&15)
  const int n2a = t >> 4, k1pa = t & 15;
  float2 ya[16] = {};
  #pragma unroll 1
  for (int n1 = 0; n1 < 16; ++n1) {
    float2 tv = tw16s[(n1 * k1pa) & 15];       // LDS broadcast
    const float2* row = &tile[(16 * n1 + n2a) * 17];
    #pragma unroll
    for (int w = 0; w < 16; ++w) {
      float2 d = row[w];
      ya[w].x += d.x * tv.x - d.y * tv.y;
      ya[w].y += d.x * tv.y + d.y * tv.x;
    }
  }
  {
    float sn, cs; sincosf(SIGN * PI2F * (float)(n2a * k1pa) / 256.f, &sn, &cs);
    #pragma unroll
    for (int w = 0; w < 16; ++w) {
      float2 a = ya[w];
      ya[w] = make_float2(a.x * cs - a.y * sn, a.x * sn + a.y * cs);
    }
  }
  __syncthreads();                       // all phase-A reads done
  {
    float2* yrow = &tile[(n2a * 16 + k1pa) * 17];
    #pragma unroll
    for (int w = 0; w < 16; ++w) yrow[w] = ya[w];
  }
  __syncthreads();                       // y visible
  // ---- phase B: thread -> (k1p = t>>4, w = t&15)
  const int k1pb = t >> 4, wB = t & 15;
  float2 acc[16] = {};
  #pragma unroll 1
  for (int n2 = 0; n2 < 16; ++n2) {
    float2 d = tile[(n2 * 16 + k1pb) * 17 + wB];
    #pragma unroll
    for (int k2p = 0; k2p < 16; ++k2p) {
      float2 tv = tw16s[(n2 * k2p) & 15];      // LDS broadcast
      acc[k2p].x += d.x * tv.x - d.y * tv.y;
      acc[k2p].y += d.x * tv.y + d.y * tv.x;
    }
  }
  const float sc = SCALE ? (1.f / 32768.f) : 1.f;
  #pragma unroll
  for (int k2p = 0; k2p < 16; ++k2p) {
    int k2 = k1pb + 16 * k2p;
    size_t row = (size_t)(k1 + 128 * k2);
    X[row * 64 + wq + wB] = make_float2(acc[k2p].x * sc, acc[k2p].y * sc);
  }
}

// ---------------------------------------------------------------------------
// Pointwise A+/- fold, lin1 crelu, Q-fold (ifft64+lin2).
// One in-place 16KB y/z tile (wave-private rows), Qt staged in LDS via DMA,
// unroll-by-4 broadcast b128 tile reads, rolling 1-ahead l1W prefetch.
// ---------------------------------------------------------------------------
__global__ __launch_bounds__(256) void pw_lin(
    const float2* __restrict__ xh,
    const float2* __restrict__ Ap, const float2* __restrict__ Am,
    const float* __restrict__ l1W, const float* __restrict__ l1b,
    const float2* __restrict__ Qt, const float2* __restrict__ b2c,
    float2* __restrict__ u)
{
  __shared__ __align__(16) float2 tile[32][64];   // y, then z in place
  __shared__ __align__(16) float2 qt[64 * 64];    // Qt[w][j], 32KB
  const int t = threadIdx.x;
  const int lane = t & 63;
  const int wv = t >> 6;
  const size_t b0 = (size_t)blockIdx.x * 32;

  // stage Qt (32KB) via async DMA: 32 x 1KB instrs, 8 per wave
  #pragma unroll
  for (int s = 0; s < 8; ++s) {
    int instr = wv * 8 + s;
    gl2lds16((const char*)Qt + instr * 1024 + lane * 16,
             (const char*)qt + instr * 1024);
  }

  // phase 0: pointwise A+/- fold -> y
  for (int it = 0; it < 8; ++it) {
    int idx = it * 256 + t;
    int r = idx >> 6, w = idx & 63;
    float2 xv = xh[(b0 + r) * 64 + w];
    float2 Aa = (xv.x >= 0.f) ? Ap[w] : Am[w];
    float2 Ab = (xv.y >= 0.f) ? Ap[w] : Am[w];
    tile[r][w] = make_float2(xv.x * Aa.x - xv.y * Ab.y,
                             xv.x * Aa.y + xv.y * Ab.x);
  }
  __syncthreads();   // y visible to all waves; Qt DMA drained (vmcnt0)

  const int n = lane, rg = wv;   // wave rg owns tile rows [8rg, 8rg+8)

  // lin1: z[r][n] = crelu(sum_w y[r][w] * l1W[n][w] + b[n]); in place.
  {
    float2 acc[8] = {};
    const float* wrow = l1W + n * 64;
    float4 lwn = *(const float4*)wrow;             // rolling prefetch
    #pragma unroll 1
    for (int w2 = 0; w2 < 16; ++w2) {
      float4 lw = lwn;
      lwn = *(const float4*)(wrow + 4 * ((w2 + 1) & 15));
      int w = 4 * w2;
      #pragma unroll
      for (int r = 0; r < 8; ++r) {
        const float4* rowp = (const float4*)(&tile[rg * 8 + r][w]);
        float4 y01 = rowp[0];                      // broadcast b128
        float4 y23 = rowp[1];
        acc[r].x += y01.x * lw.x + y01.z * lw.y + y23.x * lw.z + y23.z * lw.w;
        acc[r].y += y01.y * lw.x + y01.w * lw.y + y23.y * lw.z + y23.w * lw.w;
      }
    }
    float bb = l1b[n];
    #pragma unroll
    for (int r = 0; r < 8; ++r) {
      float zr = acc[r].x + bb; zr = zr > 0.f ? zr : 0.f;
      float zi = acc[r].y;      zi = zi > 0.f ? zi : 0.f;
      tile[rg * 8 + r][n] = make_float2(zr, zi);   // same-wave rows only
    }
  }

  // Q-fold: u[r][j] = sum_w z[r][w] * Qt[w][j] + b2c[j]
  {
    const int j = lane;
    float2 acc[8] = {};
    #pragma unroll 1
    for (int w2 = 0; w2 < 16; ++w2) {
      int w = 4 * w2;
      float2 q0 = qt[(w + 0) * 64 + j];            // contiguous per-lane b64
      float2 q1 = qt[(w + 1) * 64 + j];
      float2 q2 = qt[(w + 2) * 64 + j];
      float2 q3 = qt[(w + 3) * 64 + j];
      #pragma unroll
      for (int r = 0; r < 8; ++r) {
        const float4* rowp = (const float4*)(&tile[rg * 8 + r][w]);
        float4 z01 = rowp[0];                      // broadcast b128
        float4 z23 = rowp[1];
        acc[r].x += z01.x * q0.x - z01.y * q0.y
                  + z01.z * q1.x - z01.w * q1.y
                  + z23.x * q2.x - z23.y * q2.y
                  + z23.z * q3.x - z23.w * q3.y;
        acc[r].y += z01.x * q0.y + z01.y * q0.x
                  + z01.z * q1.y + z01.w * q1.x
                  + z23.x * q2.y + z23.y * q2.x
                  + z23.z * q3.y + z23.w * q3.x;
      }
    }
    float2 bc = b2c[j];
    #pragma unroll
    for (int r = 0; r < 8; ++r)
      u[(b0 + rg * 8 + r) * 64 + j] = make_float2(acc[r].x + bc.x, acc[r].y + bc.y);
  }
}

// ---------------------------------------------------------------------------
// Final W_out GEMM; MODE 0 = real only, MODE 1 = interleaved (re,im).
// 1024 blocks x 32 rows, unroll-by-2 broadcast b128 reads, rolling prefetch.
// ---------------------------------------------------------------------------
template<int MODE>
__global__ __launch_bounds__(256) void final_out(
    const float2* __restrict__ v, const float* __restrict__ Wout,
    const float* __restrict__ bout, float* __restrict__ out)
{
  __shared__ __align__(16) float2 vt[32][64];
  const int t = threadIdx.x;
  const size_t b0 = (size_t)blockIdx.x * 32;
  for (int it = 0; it < 8; ++it) {
    int idx = it * 256 + t;
    int r = idx >> 6, w = idx & 63;
    vt[r][w] = v[(b0 + r) * 64 + w];
  }
  __syncthreads();
  const int f = t & 127, rg = t >> 7;
  const float* wrow = Wout + f * 64;
  float2 acc[16] = {};
  float2 wvn = *(const float2*)wrow;               // rolling prefetch
  #pragma unroll 1
  for (int j2 = 0; j2 < 32; ++j2) {
    float2 wc = wvn;
    wvn = *(const float2*)(wrow + 2 * ((j2 + 1) & 31));
    #pragma unroll
    for (int r = 0; r < 16; ++r) {
      float4 vv = *(const float4*)(&vt[rg * 16 + r][2 * j2]);  // broadcast b128
      acc[r].x += vv.x * wc.x + vv.z * wc.y;
      acc[r].y += vv.y * wc.x + vv.w * wc.y;
    }
  }
  float bb = bout[f];
  #pragma unroll
  for (int r = 0; r < 16; ++r) {
    size_t idx = (b0 + rg * 16 + r) * 128 + f;
    if (MODE == 0) out[idx] = acc[r].x + bb;
    else ((float2*)out)[idx] = make_float2(acc[r].x + bb, acc[r].y);
  }
}

// ---------------------------------------------------------------------------
extern "C" void kernel_launch(void* const* d_in, const int* in_sizes, int n_in,
                              void* d_out, int out_size, void* d_ws, size_t ws_size,
                              hipStream_t stream)
{
  (void)in_sizes; (void)n_in; (void)ws_size;
  const float* geom = (const float*)d_in[0];
  const float* Win  = (const float*)d_in[1];
  const float* bin  = (const float*)d_in[2];
  const float* Wh1  = (const float*)d_in[3];
  const float* bh1  = (const float*)d_in[4];
  const float* Wh2  = (const float*)d_in[5];
  const float* bh2  = (const float*)d_in[6];
  const float* w0   = (const float*)d_in[7];
  const float* w1   = (const float*)d_in[8];
  const float* l1W  = (const float*)d_in[9];
  const float* l1b  = (const float*)d_in[10];
  const float* l2W  = (const float*)d_in[11];
  const float* l2b  = (const float*)d_in[12];
  const float* Wout = (const float*)d_in[13];
  const float* bout = (const float*)d_in[14];

  char* ws = (char*)d_ws;
  const size_t MB = 1048576ull;
  unsigned short* geomb = (unsigned short*)(ws);
  unsigned short* x2b   = (unsigned short*)(ws);
  unsigned short* x1b   = (unsigned short*)(ws + 32 * MB);
  float*  x3  = (float*)(ws + 32 * MB);
  float2* S0  = (float2*)(ws + 40 * MB);
  float2* S1  = (float2*)(ws + 56 * MB);
  float2* Ap  = (float2*)(ws + 72 * MB);
  float2* Am  = (float2*)(ws + 72 * MB + 512);
  float2* b2c = (float2*)(ws + 72 * MB + 1024);
  float2* Qt  = (float2*)(ws + 72 * MB + 1536);
  unsigned short* Winb = (unsigned short*)(ws + 96 * MB);
  unsigned short* Wh1b = (unsigned short*)(ws + 97 * MB);
  unsigned short* Wh2b = (unsigned short*)(ws + 98 * MB);

  f32_to_bf16_k<<<16384, 256, 0, stream>>>(geom, geomb, 4194304);
  f32_to_bf16_k<<<512, 256, 0, stream>>>(Win, Winb, 131072);
  f32_to_bf16_k<<<512, 256, 0, stream>>>(Wh1, Wh1b, 131072);
  f32_to_bf16_k<<<32, 256, 0, stream>>>(Wh2, Wh2b, 8192);

  // GEMM1: [32768,512] x [1024,512]^T -> bf16 [32768,1024]
  gemm256_db<unsigned short><<<dim3(128, 4), 512, 0, stream>>>(
      geomb, Winb, bin, x1b, 1024, 512);
  // GEMM2: [32768,1024] x [512,1024]^T -> bf16 [32768,512]
  gemm256_db<unsigned short><<<dim3(128, 2), 512, 0, stream>>>(
      x1b, Wh1b, bh1, x2b, 512, 1024);
  // GEMM3: [32768,512] x [64,512]^T -> f32 [32768,64]
  gemm_async<128, 64,64,32,float><<<dim3(256, 1), 256, 0, stream>>>(
      x2b, Wh2b, bh2, x3, 32768, 64, 512);

  precompute<<<17, 256, 0, stream>>>(w0, w1, l2W, l2b, Ap, Am, Qt, b2c);
  dft64_rows<<<1024, 256, 0, stream>>>(x3, S0);
  fft_stage1<-1><<<512, 256, 0, stream>>>(S0, S1);
  fft_stage2<-1, false><<<512, 256, 0, stream>>>(S1, S0);
  pw_lin<<<1024, 256, 0, stream>>>(S0, Ap, Am, l1W, l1b, Qt, b2c, S1);
  fft_stage1<1><<<512, 256, 0, stream>>>(S1, S0);
  fft_stage2<1, true><<<512, 256, 0, stream>>>(S0, S1);
  if (out_size >= 8388608) {
    final_out<1><<<1024, 256, 0, stream>>>(S1, Wout, bout, (float*)d_out);
  } else {
    final_out<0><<<1024, 256, 0, stream>>>(S1, Wout, bout, (float*)d_out);
  }
}